// Round 3
// baseline (341.884 us; speedup 1.0000x reference)
//
#include <hip/hip_runtime.h>
#include <hip/hip_bf16.h>
#include <math.h>

#define SQ 4096
#define DM 1024
#define NH 16
// DH = 64

typedef unsigned int uint32;
typedef unsigned short u16;
typedef __attribute__((ext_vector_type(8))) __bf16 bf16x8;
typedef __attribute__((ext_vector_type(4))) __bf16 bf16x4;
typedef __attribute__((ext_vector_type(4))) float f32x4;
typedef __attribute__((ext_vector_type(4))) short s16x4;
typedef __attribute__((ext_vector_type(8))) unsigned short u16x8;
typedef __attribute__((ext_vector_type(4))) unsigned short u16x4;

__device__ __forceinline__ u16 f2bf(float f) {
  uint32 u = __builtin_bit_cast(uint32, f);
  u += 0x7FFFu + ((u >> 16) & 1u);   // RNE
  return (u16)(u >> 16);
}

__device__ __forceinline__ void gld16(const void* g, void* l) {
  __builtin_amdgcn_global_load_lds((const __attribute__((address_space(1))) void*)g,
                                   (__attribute__((address_space(3))) void*)l, 16, 0, 0);
}

__device__ __forceinline__ f32x4 mfma32(bf16x8 a, bf16x8 b, f32x4 c) {
  return __builtin_amdgcn_mfma_f32_16x16x32_bf16(a, b, c, 0, 0, 0);
}

// v_mfma_f32_16x16x16_bf16 (gfx90a+ "_1k" spelling; A/B = 4 bf16 as short4)
__device__ __forceinline__ f32x4 mfma16(s16x4 a, s16x4 b, f32x4 c) {
  return __builtin_amdgcn_mfma_f32_16x16x16bf16_1k(a, b, c, 0, 0, 0);
}

// ---------------- fp32 -> bf16 convert (optionally scaled) ----------------
__global__ void cvt_kernel(const float* __restrict__ src, u16* __restrict__ dst, int n4, float scale) {
  int i = blockIdx.x * blockDim.x + threadIdx.x;
  if (i < n4) {
    float4 v = reinterpret_cast<const float4*>(src)[i];
    u16x4 o = { f2bf(v.x * scale), f2bf(v.y * scale), f2bf(v.z * scale), f2bf(v.w * scale) };
    reinterpret_cast<u16x4*>(dst)[i] = o;
  }
}

// ---------------- RoPE cos/sin table: tab[s*32+p] = (cos, sin)(s * 10000^(-p/32)) ----------------
__global__ void rope_tab_kernel(float2* __restrict__ tab) {
  int t = blockIdx.x * blockDim.x + threadIdx.x; // SQ*32 threads
  int s = t >> 5, p = t & 31;
  double inv = pow(10000.0, -(double)p / 32.0);
  float ang = (float)s * (float)inv;
  tab[t] = make_float2(cosf(ang), sinf(ang));
}

// ---------------- 128x128xK GEMM core (NT: C[s][i] = sum_k A[s][k]*B[i][k]) ----------------
// m97 structure: global_load_lds width16 staging, [128][32] bf16 LDS tiles, 4 waves 2x2,
// each wave 64x64 via 4x4 frags of 16x16x32 MFMA.
__device__ __forceinline__ void gemm_core(const u16* __restrict__ Ag, const u16* __restrict__ Bg,
                                          u16* As, u16* Bs, f32x4 (&acc)[4][4], int s0, int i0) {
  const int tid = threadIdx.x;
  const int lane = tid & 63;
  const int wv = tid >> 6;
  const int wr = wv >> 1, wc = wv & 1;
  const int r15 = lane & 15, g = lane >> 4;
  const int srow = tid >> 2;
  const int schk = (tid & 3) * 8;

  for (int k0 = 0; k0 < DM; k0 += 32) {
#pragma unroll
    for (int half = 0; half < 2; ++half) {
      gld16(Ag + (size_t)(s0 + half * 64 + srow) * DM + k0 + schk, As + (half * 256 + wv * 64) * 8);
      gld16(Bg + (size_t)(i0 + half * 64 + srow) * DM + k0 + schk, Bs + (half * 256 + wv * 64) * 8);
    }
    __syncthreads();   // drains vmcnt -> tiles ready
    bf16x8 af[4], bfr[4];
#pragma unroll
    for (int m = 0; m < 4; ++m)
      af[m] = *reinterpret_cast<const bf16x8*>(As + (wr * 64 + m * 16 + r15) * 32 + g * 8);
#pragma unroll
    for (int n = 0; n < 4; ++n)
      bfr[n] = *reinterpret_cast<const bf16x8*>(Bs + (wc * 64 + n * 16 + r15) * 32 + g * 8);
#pragma unroll
    for (int m = 0; m < 4; ++m)
#pragma unroll
      for (int n = 0; n < 4; ++n)
        acc[m][n] = mfma32(af[m], bfr[n], acc[m][n]);
    __syncthreads();   // LDS free for next stage
  }
}

// ---------------- projections: z=0 Q(rope), z=1 K(rope), z=2 V(transposed [h][dh][s]) ----------------
__global__ __launch_bounds__(256) void proj_kernel(
    const u16* __restrict__ qb, const u16* __restrict__ kb, const u16* __restrict__ vb,
    const u16* __restrict__ Wq, const u16* __restrict__ Wk, const u16* __restrict__ Wv,
    u16* __restrict__ Xq, u16* __restrict__ Xk, u16* __restrict__ Vt,
    const float2* __restrict__ tab) {
  __shared__ u16 As[128 * 32], Bs[128 * 32];
  const int z = blockIdx.z;
  const u16* Ag = (z == 0) ? qb : (z == 1) ? kb : vb;
  const u16* Bg = (z == 0) ? Wq : (z == 1) ? Wk : Wv;
  const int s0 = blockIdx.x * 128, i0 = blockIdx.y * 128;
  f32x4 acc[4][4] = {};
  gemm_core(Ag, Bg, As, Bs, acc, s0, i0);

  const int tid = threadIdx.x, lane = tid & 63, wv = tid >> 6;
  const int wr = wv >> 1, wc = wv & 1, r15 = lane & 15, g = lane >> 4;
  if (z < 2) {
    u16* dst = (z == 0) ? Xq : Xk;
#pragma unroll
    for (int m = 0; m < 4; ++m) {
#pragma unroll
      for (int n = 0; n < 4; ++n) {
        int i = i0 + wc * 64 + n * 16 + r15;
        int p = (i & 63) >> 1;
#pragma unroll
        for (int r = 0; r < 4; ++r) {
          int s = s0 + wr * 64 + m * 16 + g * 4 + r;
          float v = acc[m][n][r];
          float o = __shfl_xor(v, 1);          // partner of rope pair (i even <-> odd)
          float2 cs = tab[s * 32 + p];
          float res = ((lane & 1) == 0) ? (v * cs.x - o * cs.y)   // real part
                                        : (o * cs.y + v * cs.x);  // imag part
          dst[(size_t)s * DM + i] = f2bf(res);
        }
      }
    }
  } else {
#pragma unroll
    for (int m = 0; m < 4; ++m) {
#pragma unroll
      for (int n = 0; n < 4; ++n) {
        int i = i0 + wc * 64 + n * 16 + r15;
        int h = i >> 6, dh = i & 63;
        int sb = s0 + wr * 64 + m * 16 + g * 4;
        u16x4 pk = { f2bf(acc[m][n][0]), f2bf(acc[m][n][1]), f2bf(acc[m][n][2]), f2bf(acc[m][n][3]) };
        *reinterpret_cast<u16x4*>(Vt + (size_t)h * (64 * SQ) + (size_t)dh * SQ + sb) = pk;
      }
    }
  }
}

// ---------------- flash attention: swapped QK^T, 4 waves x 16 q-rows, KV tile = 64 ----------------
__global__ __launch_bounds__(256) void attn_kernel(const u16* __restrict__ Xq, const u16* __restrict__ Xk,
                                                   const u16* __restrict__ Vt, u16* __restrict__ Ob) {
  __shared__ u16 Ks[64 * 64], Vs[64 * 64];  // [row][64] bf16, XOR-swizzled
  const int tid = threadIdx.x, lane = tid & 63, wv = tid >> 6;
  const int r15 = lane & 15, g = lane >> 4;
  const int h = blockIdx.y;
  const int q0 = blockIdx.x * 64 + wv * 16;

  // Q fragments in registers for the whole KV loop (B-operand: col=q=lane&15, k=dh)
  bf16x8 qf[2];
#pragma unroll
  for (int kc = 0; kc < 2; ++kc)
    qf[kc] = *reinterpret_cast<const bf16x8*>(Xq + (size_t)(q0 + r15) * DM + h * 64 + kc * 32 + g * 8);

  f32x4 oacc[4] = {};
  float m_run = -3e38f, l_run = 0.f;

  u16x8 kst[2], vst[2];
  auto ldregs = [&](int t) {
#pragma unroll
    for (int j = 0; j < 2; ++j) {
      int c = tid + j * 256, row = c >> 3, ch = c & 7;
      kst[j] = *reinterpret_cast<const u16x8*>(Xk + (size_t)(t * 64 + row) * DM + h * 64 + ch * 8);
      vst[j] = *reinterpret_cast<const u16x8*>(Vt + (size_t)h * (64 * SQ) + (size_t)row * SQ + t * 64 + ch * 8);
    }
  };
  ldregs(0);

  for (int t = 0; t < 64; ++t) {
    __syncthreads();  // previous tile's LDS reads done
#pragma unroll
    for (int j = 0; j < 2; ++j) {
      int c = tid + j * 256, row = c >> 3, ch = c & 7;
      int byt = (row * 128 + ch * 16) ^ ((row & 7) << 4);
      *reinterpret_cast<u16x8*>(reinterpret_cast<char*>(Ks) + byt) = kst[j];
      *reinterpret_cast<u16x8*>(reinterpret_cast<char*>(Vs) + byt) = vst[j];
    }
    __syncthreads();  // tile ready
    if (t < 63) ldregs(t + 1);  // async-split: next tile's HBM latency hides under compute

    // S^T[key][q] = sum_dh K[key][dh]*Q[q][dh]  (scale folded into Wq)
    f32x4 sa[4] = {};
#pragma unroll
    for (int kc = 0; kc < 2; ++kc) {
#pragma unroll
      for (int km = 0; km < 4; ++km) {
        int row = km * 16 + r15;
        int byt = (row * 128 + kc * 64 + g * 16) ^ ((row & 7) << 4);
        bf16x8 kf = *reinterpret_cast<const bf16x8*>(reinterpret_cast<const char*>(Ks) + byt);
        sa[km] = mfma32(kf, qf[kc], sa[km]);
      }
    }
    // lane-local online softmax for q = lane&15 (16 scores/lane; row spread over lanes l^16,l^32)
    float mx = -3e38f;
#pragma unroll
    for (int km = 0; km < 4; ++km)
#pragma unroll
      for (int r = 0; r < 4; ++r) mx = fmaxf(mx, sa[km][r]);
    mx = fmaxf(mx, __shfl_xor(mx, 16));
    mx = fmaxf(mx, __shfl_xor(mx, 32));
    float mnew = fmaxf(m_run, mx);
    float p[16], psum = 0.f;
#pragma unroll
    for (int km = 0; km < 4; ++km)
#pragma unroll
      for (int r = 0; r < 4; ++r) {
        float e = __expf(sa[km][r] - mnew);
        p[km * 4 + r] = e;
        psum += e;
      }
    psum += __shfl_xor(psum, 16);
    psum += __shfl_xor(psum, 32);
    float fac = __expf(m_run - mnew);
    l_run = l_run * fac + psum;
    m_run = mnew;
    // rescale O: O's q-row is (g*4+r) -> broadcast fac from lane q
#pragma unroll
    for (int r = 0; r < 4; ++r) {
      float fr = __shfl(fac, g * 4 + r);
#pragma unroll
      for (int n = 0; n < 4; ++n) oacc[n][r] *= fr;
    }
    // PV with 16x16x16: A = P (row=q=lane&15, k=key=(g*4+e)) -- exactly the S^T layout
#pragma unroll
    for (int kk = 0; kk < 4; ++kk) {
      s16x4 pa = { (short)f2bf(p[kk * 4 + 0]), (short)f2bf(p[kk * 4 + 1]),
                   (short)f2bf(p[kk * 4 + 2]), (short)f2bf(p[kk * 4 + 3]) };
#pragma unroll
      for (int n = 0; n < 4; ++n) {
        int vrow = n * 16 + r15;
        int byt = (vrow * 128 + kk * 32 + g * 8) ^ ((vrow & 7) << 4);
        s16x4 vfr = *reinterpret_cast<const s16x4*>(reinterpret_cast<const char*>(Vs) + byt);
        oacc[n] = mfma16(pa, vfr, oacc[n]);
      }
    }
  }

  float linv = 1.f / l_run;
#pragma unroll
  for (int r = 0; r < 4; ++r) {
    float lr = __shfl(linv, g * 4 + r);
#pragma unroll
    for (int n = 0; n < 4; ++n) {
      int q = q0 + g * 4 + r;
      int dh = n * 16 + r15;
      Ob[(size_t)q * DM + h * 64 + dh] = f2bf(oacc[n][r] * lr);
    }
  }
}

// ---------------- output projection + bias, fp32 out ----------------
__global__ __launch_bounds__(256) void out_kernel(const u16* __restrict__ Ob, const u16* __restrict__ Wo,
                                                  float* __restrict__ out, const float* __restrict__ bias) {
  __shared__ u16 As[128 * 32], Bs[128 * 32];
  const int s0 = blockIdx.x * 128, i0 = blockIdx.y * 128;
  f32x4 acc[4][4] = {};
  gemm_core(Ob, Wo, As, Bs, acc, s0, i0);
  const int tid = threadIdx.x, lane = tid & 63, wv = tid >> 6;
  const int wr = wv >> 1, wc = wv & 1, r15 = lane & 15, g = lane >> 4;
#pragma unroll
  for (int m = 0; m < 4; ++m) {
#pragma unroll
    for (int n = 0; n < 4; ++n) {
      int i = i0 + wc * 64 + n * 16 + r15;
      float bv = bias[i];
#pragma unroll
      for (int r = 0; r < 4; ++r) {
        int s = s0 + wr * 64 + m * 16 + g * 4 + r;
        out[(size_t)s * DM + i] = acc[m][n][r] + bv;
      }
    }
  }
}

extern "C" void kernel_launch(void* const* d_in, const int* in_sizes, int n_in,
                              void* d_out, int out_size, void* d_ws, size_t ws_size,
                              hipStream_t stream) {
  const float* q  = (const float*)d_in[0];
  const float* k  = (const float*)d_in[1];
  const float* v  = (const float*)d_in[2];
  const float* Wq = (const float*)d_in[3];
  const float* Wk = (const float*)d_in[4];
  const float* Wv = (const float*)d_in[5];
  const float* Wo = (const float*)d_in[6];
  const float* bo = (const float*)d_in[7];
  float* out = (float*)d_out;

  char* ws = (char*)d_ws;
  size_t off = 0;
  auto alloc = [&](size_t bytes) { char* p = ws + off; off += (bytes + 255) & ~(size_t)255; return p; };
  u16* qb  = (u16*)alloc((size_t)SQ * DM * 2);
  u16* kb  = (u16*)alloc((size_t)SQ * DM * 2);
  u16* vb  = (u16*)alloc((size_t)SQ * DM * 2);
  u16* Wqb = (u16*)alloc((size_t)DM * DM * 2);
  u16* Wkb = (u16*)alloc((size_t)DM * DM * 2);
  u16* Wvb = (u16*)alloc((size_t)DM * DM * 2);
  u16* Wob = (u16*)alloc((size_t)DM * DM * 2);
  u16* Xq  = (u16*)alloc((size_t)SQ * DM * 2);
  u16* Xk  = (u16*)alloc((size_t)SQ * DM * 2);
  u16* Vt  = (u16*)alloc((size_t)SQ * DM * 2);
  float2* tab = (float2*)alloc((size_t)SQ * 32 * sizeof(float2));
  u16* Ob = qb;  // qb is dead after proj_kernel; reuse for attention output

  const int nbig = SQ * DM / 4;  // float4 chunks
  const int nw = DM * DM / 4;
  cvt_kernel<<<nbig / 256, 256, 0, stream>>>(q, qb, nbig, 1.0f);
  cvt_kernel<<<nbig / 256, 256, 0, stream>>>(k, kb, nbig, 1.0f);
  cvt_kernel<<<nbig / 256, 256, 0, stream>>>(v, vb, nbig, 1.0f);
  cvt_kernel<<<nw / 256, 256, 0, stream>>>(Wq, Wqb, nw, 0.125f);  // fold 1/sqrt(DH)
  cvt_kernel<<<nw / 256, 256, 0, stream>>>(Wk, Wkb, nw, 1.0f);
  cvt_kernel<<<nw / 256, 256, 0, stream>>>(Wv, Wvb, nw, 1.0f);
  cvt_kernel<<<nw / 256, 256, 0, stream>>>(Wo, Wob, nw, 1.0f);
  rope_tab_kernel<<<(SQ * 32) / 256, 256, 0, stream>>>(tab);

  proj_kernel<<<dim3(32, 8, 3), 256, 0, stream>>>(qb, kb, vb, Wqb, Wkb, Wvb, Xq, Xk, Vt, tab);
  attn_kernel<<<dim3(64, 16), 256, 0, stream>>>(Xq, Xk, Vt, Ob);
  out_kernel<<<dim3(32, 8), 256, 0, stream>>>(Ob, Wob, out, bo);
}